// Round 13
// baseline (311.165 us; speedup 1.0000x reference)
//
#include <hip/hip_runtime.h>

#define NN 50000
#define NE 800000
#define INF 128
#define HF 64
#define K2 192
#define MAXDEG 64
#define NBINS 65

typedef __attribute__((ext_vector_type(8))) short short8;
typedef __attribute__((ext_vector_type(4))) float float4v;
typedef __attribute__((ext_vector_type(4))) unsigned short ushort4v;
typedef __attribute__((ext_vector_type(2))) unsigned int uint2v;

// float -> bf16 bits, round-to-nearest-even (data has no NaN/Inf)
__device__ inline unsigned short f2bf(float x) {
    unsigned int u = __float_as_uint(x);
    u += 0x7FFFu + ((u >> 16) & 1u);
    return (unsigned short)(u >> 16);
}
__device__ inline float bflo(unsigned int p) { return __uint_as_float(p << 16); }
__device__ inline float bfhi(unsigned int p) { return __uint_as_float(p & 0xFFFF0000u); }

// ---------------- ELL build (ushort ids), XCD-partitioned (round-7 win) ----------------

__global__ __launch_bounds__(256) void fill_ell_part(const int* __restrict__ src,
                                                     const int* __restrict__ dst,
                                                     int* __restrict__ cnt,
                                                     unsigned short* __restrict__ ell) {
    int chunk = blockIdx.x >> 3;
    int p     = blockIdx.x & 7;
    int e = chunk * 256 + threadIdx.x;
    if (e >= NE) return;
    int d = dst[e];
    if (d / 6250 != p) return;
    int pos = atomicAdd(&cnt[d], 1);
    if (pos < MAXDEG) ell[d * MAXDEG + pos] = (unsigned short)src[e];
}

// deg clamp + D^{-1/2} + degree histogram (LDS-aggregated) + sentinel zeroing
__global__ __launch_bounds__(256) void dinv_kernel(int* __restrict__ cnt,
                                                   float* __restrict__ dinv,
                                                   int* __restrict__ hist,
                                                   unsigned short* __restrict__ hb0,
                                                   unsigned short* __restrict__ hb1) {
    __shared__ int lh[NBINS];
    int tid = threadIdx.x;
    if (tid < NBINS) lh[tid] = 0;
    __syncthreads();
    int i = blockIdx.x * 256 + tid;
    if (i < NN) {
        int c = cnt[i];
        if (c > MAXDEG) c = MAXDEG;
        cnt[i] = c;
        dinv[i] = rsqrtf((float)(c < 1 ? 1 : c));
        atomicAdd(&lh[c], 1);
    }
    if (i < HF) {
        hb0[(size_t)NN * HF + i] = 0;
        hb1[(size_t)NN * HF + i] = 0;
    }
    __syncthreads();
    if (tid < NBINS && lh[tid] > 0) atomicAdd(&hist[tid], lh[tid]);
}

// one wave: exclusive scan of the 65-bin histogram -> bin cursors
__global__ __launch_bounds__(64) void scan_bins(const int* __restrict__ hist,
                                                int* __restrict__ cursor) {
    int t = threadIdx.x;            // 0..63
    int v = hist[t];
    int s = v;
#pragma unroll
    for (int off = 1; off < 64; off <<= 1) {
        int u = __shfl_up(s, off);
        if (t >= off) s += u;
    }
    cursor[t] = s - v;              // exclusive prefix for bins 0..63
    if (t == 63) cursor[64] = s;    // bin 64 starts after all of 0..63
}

// scatter node ids into degree-sorted permutation
__global__ __launch_bounds__(256) void perm_fill(const int* __restrict__ cnt,
                                                 int* __restrict__ cursor,
                                                 int* __restrict__ perm) {
    int i = blockIdx.x * 256 + threadIdx.x;
    if (i >= NN) return;
    int pos = atomicAdd(&cursor[cnt[i]], 1);
    perm[pos] = i;
}

// ---------------- merged B-fragment pack + cnt/hist zero-init ----------------
// frag index: [kc][nt][lane][j], value = B[k = kc*32 + (lane>>4)*8 + j][n = nt*16 + (lane&15)]

__global__ void pack_b(const float* __restrict__ W1, const float* __restrict__ W2,
                       unsigned short* __restrict__ Bp1, unsigned short* __restrict__ Bp2,
                       int* __restrict__ cnt, int* __restrict__ hist) {
    int gid = blockIdx.x * 256 + threadIdx.x;  // 80*256 = 20480 threads
    // zero cnt (NN) and hist (NBINS) with grid-stride
    for (int z = gid; z < NN + NBINS; z += 20480) {
        if (z < NN) cnt[z] = 0;
        else        hist[z - NN] = 0;
    }
    if (gid >= 20480) return;
    if (gid < 8192) {
        int j  = gid & 7;
        int l  = (gid >> 3) & 63;
        int nt = (gid >> 9) & 3;
        int kc = gid >> 11;
        int n = nt * 16 + (l & 15);
        int k = kc * 32 + (l >> 4) * 8 + j;
        Bp1[gid] = f2bf(W1[n * INF + k]);  // B[k][n] = W1[n][k]
    } else {
        int g = gid - 8192;
        int j  = g & 7;
        int l  = (g >> 3) & 63;
        int nt = (g >> 9) & 3;
        int kc = g >> 11;  // 0..5
        int n = nt * 16 + (l & 15);
        int k = kc * 32 + (l >> 4) * 8 + j;  // 0..191
        const float* row = W2 + (size_t)n * K2;
        float v;
        if (k < 64) {
            v = 3.0f * row[k];
        } else if (k < 128) {
            int c = k - 64;
            v = -3.0f * row[c] + 3.0f * row[64 + c];
        } else {
            int c = k - 128;
            v = 0.75f * row[c] - 1.5f * row[64 + c] + 0.75f * row[128 + c];
        }
        Bp2[g] = f2bf(v);
    }
}

// ---------------- GEMM1 (MFMA): xb = relu(F@W1^T+b1), hb0 = xb*dinv (both bf16) ----

__global__ __launch_bounds__(256) void gemm1_mfma(const float* __restrict__ F,
                                                  const unsigned short* __restrict__ Bp,
                                                  const float* __restrict__ b1,
                                                  const float* __restrict__ dinv,
                                                  unsigned short* __restrict__ xb,
                                                  unsigned short* __restrict__ hb0) {
    int tid  = threadIdx.x;
    int lane = tid & 63;
    int wv   = tid >> 6;
    int m0   = blockIdx.x * 64 + wv * 16;
    if (m0 >= NN) return;                 // NN % 16 == 0
    int mrow = lane & 15;
    int q    = lane >> 4;

    float4v acc[4];
#pragma unroll
    for (int nt = 0; nt < 4; ++nt) acc[nt] = (float4v){0.f, 0.f, 0.f, 0.f};

    const float* arow = F + (size_t)(m0 + mrow) * INF + q * 8;
#pragma unroll
    for (int kc = 0; kc < INF / 32; ++kc) {
        const float* ap = arow + kc * 32;
        float4v a0 = *reinterpret_cast<const float4v*>(ap);
        float4v a1 = *reinterpret_cast<const float4v*>(ap + 4);
        short8 af;
        af[0] = (short)f2bf(a0[0]); af[1] = (short)f2bf(a0[1]);
        af[2] = (short)f2bf(a0[2]); af[3] = (short)f2bf(a0[3]);
        af[4] = (short)f2bf(a1[0]); af[5] = (short)f2bf(a1[1]);
        af[6] = (short)f2bf(a1[2]); af[7] = (short)f2bf(a1[3]);
#pragma unroll
        for (int nt = 0; nt < 4; ++nt) {
            short8 bf = *reinterpret_cast<const short8*>(Bp + (((kc * 4 + nt) * 64 + lane) << 3));
            acc[nt] = __builtin_amdgcn_mfma_f32_16x16x32_bf16(af, bf, acc[nt], 0, 0, 0);
        }
    }

    float dn[4];
#pragma unroll
    for (int r = 0; r < 4; ++r) dn[r] = dinv[m0 + q * 4 + r];

#pragma unroll
    for (int nt = 0; nt < 4; ++nt) {
        int n = nt * 16 + mrow;
        float bv = b1[n];
#pragma unroll
        for (int r = 0; r < 4; ++r) {
            int node = m0 + q * 4 + r;
            float v = acc[nt][r] + bv;
            v = v > 0.0f ? v : 0.0f;
            xb [(size_t)node * HF + n] = f2bf(v);
            hb0[(size_t)node * HF + n] = f2bf(v * dn[r]);
        }
    }
}

// ---------------- quad gather, degree-sorted: 4 nodes/wave, 16 lanes/node ----
// Nodes processed in degree-sorted order (perm) so the wave-max loop bound
// ~= mean degree instead of max-of-4. Out-of-degree slots -> zero sentinel NN.

template <bool WRITE_H>
__global__ __launch_bounds__(256) void gather_quad(const int* __restrict__ perm,
                                                   const unsigned short* __restrict__ ell,
                                                   const int* __restrict__ cnt,
                                                   const float* __restrict__ dinv,
                                                   const unsigned short* __restrict__ fin,
                                                   const unsigned short* __restrict__ hb,
                                                   unsigned short* __restrict__ fout,
                                                   unsigned short* __restrict__ hout) {
    int lane  = threadIdx.x & 63;
    int wv    = threadIdx.x >> 6;
    int which = lane >> 4;        // 0..3: which node of the quad
    int jj    = lane & 15;        // 8B chunk index within 128B row
    int n = perm[blockIdx.x * 16 + wv * 4 + which];   // 3125*16 = 50000
    int deg = cnt[n];

    ushort4v ids = *reinterpret_cast<const ushort4v*>(ell + (size_t)n * MAXDEG + jj * 4);
    int slot = jj * 4;
    int s0 = (slot + 0 < deg) ? (int)ids[0] : NN;
    int s1 = (slot + 1 < deg) ? (int)ids[1] : NN;
    int s2 = (slot + 2 < deg) ? (int)ids[2] : NN;
    int s3 = (slot + 3 < deg) ? (int)ids[3] : NN;

    // wave-max degree (sorted order -> nearly uniform)
    int wmax = deg;
    wmax = max(wmax, __shfl_xor(wmax, 16));
    wmax = max(wmax, __shfl_xor(wmax, 32));

    const uint2v* hbd = (const uint2v*)hb;   // row stride 16 x 8B
    int base = which * 16;

    float a0=0,a1=0,a2=0,a3=0;
    float b0=0,b1=0,b2=0,b3=0;
    float c0=0,c1=0,c2=0,c3=0;
    float d0=0,d1=0,d2=0,d3=0;

    for (int k = 0; k < wmax; k += 4) {
        int o = base + (k >> 2);
        int t0 = __shfl(s0, o), t1 = __shfl(s1, o);
        int t2 = __shfl(s2, o), t3 = __shfl(s3, o);
        uint2v p0 = hbd[(size_t)t0 * 16 + jj];
        uint2v p1 = hbd[(size_t)t1 * 16 + jj];
        uint2v p2 = hbd[(size_t)t2 * 16 + jj];
        uint2v p3 = hbd[(size_t)t3 * 16 + jj];
        a0 += bflo(p0[0]); a1 += bfhi(p0[0]); a2 += bflo(p0[1]); a3 += bfhi(p0[1]);
        b0 += bflo(p1[0]); b1 += bfhi(p1[0]); b2 += bflo(p1[1]); b3 += bfhi(p1[1]);
        c0 += bflo(p2[0]); c1 += bfhi(p2[0]); c2 += bflo(p2[1]); c3 += bfhi(p2[1]);
        d0 += bflo(p3[0]); d1 += bfhi(p3[0]); d2 += bflo(p3[1]); d3 += bfhi(p3[1]);
    }
    float e0 = (a0 + b0) + (c0 + d0);
    float e1 = (a1 + b1) + (c1 + d1);
    float e2 = (a2 + b2) + (c2 + d2);
    float e3 = (a3 + b3) + (c3 + d3);
    float dn = dinv[n];

    uint2v xv = ((const uint2v*)fin)[(size_t)n * 16 + jj];
    float f0 = bflo(xv[0]) - e0 * dn;
    float f1 = bfhi(xv[0]) - e1 * dn;
    float f2 = bflo(xv[1]) - e2 * dn;
    float f3 = bfhi(xv[1]) - e3 * dn;
    uint2v ov;
    ov[0] = (unsigned int)f2bf(f0) | ((unsigned int)f2bf(f1) << 16);
    ov[1] = (unsigned int)f2bf(f2) | ((unsigned int)f2bf(f3) << 16);
    ((uint2v*)fout)[(size_t)n * 16 + jj] = ov;
    if (WRITE_H) {
        uint2v hv;
        hv[0] = (unsigned int)f2bf(f0 * dn) | ((unsigned int)f2bf(f1 * dn) << 16);
        hv[1] = (unsigned int)f2bf(f2 * dn) | ((unsigned int)f2bf(f3 * dn) << 16);
        ((uint2v*)hout)[(size_t)n * 16 + jj] = hv;
    }
}

// ---------------- GEMM2 (MFMA): out = [xb|f1b|f2b] @ McT + b2 ----------------

__global__ __launch_bounds__(256) void gemm2_mfma(const unsigned short* __restrict__ xb,
                                                  const unsigned short* __restrict__ f1b,
                                                  const unsigned short* __restrict__ f2b,
                                                  const unsigned short* __restrict__ Bp,
                                                  const float* __restrict__ b2,
                                                  float* __restrict__ out) {
    int tid  = threadIdx.x;
    int lane = tid & 63;
    int wv   = tid >> 6;
    int m0   = blockIdx.x * 64 + wv * 16;
    if (m0 >= NN) return;
    int mrow = lane & 15;
    int q    = lane >> 4;

    float4v acc[4];
#pragma unroll
    for (int nt = 0; nt < 4; ++nt) acc[nt] = (float4v){0.f, 0.f, 0.f, 0.f};

    const unsigned short* ax = xb  + (size_t)(m0 + mrow) * HF + q * 8;
    const unsigned short* a1 = f1b + (size_t)(m0 + mrow) * HF + q * 8;
    const unsigned short* a2 = f2b + (size_t)(m0 + mrow) * HF + q * 8;

#pragma unroll
    for (int kc = 0; kc < 6; ++kc) {
        short8 af;
        if (kc < 2)      af = *reinterpret_cast<const short8*>(ax + kc * 32);
        else if (kc < 4) af = *reinterpret_cast<const short8*>(a1 + (kc - 2) * 32);
        else             af = *reinterpret_cast<const short8*>(a2 + (kc - 4) * 32);
#pragma unroll
        for (int nt = 0; nt < 4; ++nt) {
            short8 bf = *reinterpret_cast<const short8*>(Bp + (((kc * 4 + nt) * 64 + lane) << 3));
            acc[nt] = __builtin_amdgcn_mfma_f32_16x16x32_bf16(af, bf, acc[nt], 0, 0, 0);
        }
    }

#pragma unroll
    for (int nt = 0; nt < 4; ++nt) {
        int n = nt * 16 + mrow;
        float bv = b2[n];
#pragma unroll
        for (int r = 0; r < 4; ++r) {
            int node = m0 + q * 4 + r;
            out[(size_t)node * HF + n] = acc[nt][r] + bv;
        }
    }
}

// ---------------- launch ----------------

extern "C" void kernel_launch(void* const* d_in, const int* in_sizes, int n_in,
                              void* d_out, int out_size, void* d_ws, size_t ws_size,
                              hipStream_t stream) {
    const float* features = (const float*)d_in[0];
    const int*   src      = (const int*)d_in[1];
    const int*   dst      = (const int*)d_in[2];
    const float* W1       = (const float*)d_in[3];
    const float* b1       = (const float*)d_in[4];
    const float* W2       = (const float*)d_in[5];
    const float* b2       = (const float*)d_in[6];
    float* out = (float*)d_out;

    // workspace layout (bf16 64-stride feature buffers; hb0/hb1 have a zero
    // sentinel row at index NN for the quad gather)
    unsigned short* xb  = (unsigned short*)d_ws;          // NN*64      f0
    unsigned short* hb0 = xb  + (size_t)NN * HF;          // (NN+1)*64  f0*dinv
    unsigned short* f1b = hb0 + (size_t)(NN + 1) * HF;    // NN*64      f1
    unsigned short* hb1 = f1b + (size_t)NN * HF;          // (NN+1)*64  f1*dinv
    unsigned short* f2b = hb1 + (size_t)(NN + 1) * HF;    // NN*64      f2
    unsigned short* Bp1 = f2b + (size_t)NN * HF;          // 8192
    unsigned short* Bp2 = Bp1 + 8192;                     // 12288
    unsigned short* ell = Bp2 + 12288;                    // NN*64 ushort
    int*   cnt    = (int*)(ell + (size_t)NN * MAXDEG);    // NN
    float* dinv   = (float*)(cnt + NN);                   // NN
    int*   hist   = (int*)(dinv + NN);                    // NBINS
    int*   cursor = hist + NBINS;                         // NBINS
    int*   perm   = cursor + NBINS;                       // NN

    // weight pack + cnt/hist zero-init (replaces memsetAsync)
    pack_b<<<80, 256, 0, stream>>>(W1, W2, Bp1, Bp2, cnt, hist);

    // ELL build (XCD-partitioned scatter, ushort ids)
    fill_ell_part<<<((NE + 255) / 256) * 8, 256, 0, stream>>>(src, dst, cnt, ell);

    // normalization + degree histogram + sentinel zero
    dinv_kernel<<<(NN + 255) / 256, 256, 0, stream>>>(cnt, dinv, hist, hb0, hb1);

    // degree-sorted permutation (counting sort)
    scan_bins<<<1, 64, 0, stream>>>(hist, cursor);
    perm_fill<<<(NN + 255) / 256, 256, 0, stream>>>(cnt, cursor, perm);

    // GEMM1 (MFMA) -> xb, hb0
    gemm1_mfma<<<(NN + 63) / 64, 256, 0, stream>>>(features, Bp1, b1, dinv, xb, hb0);

    // Laplacian chain: degree-sorted quad gathers
    gather_quad<true ><<<NN / 16, 256, 0, stream>>>(perm, ell, cnt, dinv, xb,  hb0, f1b, hb1);
    gather_quad<false><<<NN / 16, 256, 0, stream>>>(perm, ell, cnt, dinv, f1b, hb1, f2b, nullptr);

    // output GEMM
    gemm2_mfma<<<(NN + 63) / 64, 256, 0, stream>>>(xb, f1b, f2b, Bp2, b2, out);
}

// Round 14
// 176.267 us; speedup vs baseline: 1.7653x; 1.7653x over previous
//
#include <hip/hip_runtime.h>

#define NN 50000
#define NE 800000
#define INF 128
#define HF 64
#define K2 192
#define MAXDEG 64
#define NBINS 65

typedef __attribute__((ext_vector_type(8))) short short8;
typedef __attribute__((ext_vector_type(4))) float float4v;
typedef __attribute__((ext_vector_type(4))) unsigned short ushort4v;
typedef __attribute__((ext_vector_type(2))) unsigned int uint2v;

// float -> bf16 bits, round-to-nearest-even (data has no NaN/Inf)
__device__ inline unsigned short f2bf(float x) {
    unsigned int u = __float_as_uint(x);
    u += 0x7FFFu + ((u >> 16) & 1u);
    return (unsigned short)(u >> 16);
}
__device__ inline float bflo(unsigned int p) { return __uint_as_float(p << 16); }
__device__ inline float bfhi(unsigned int p) { return __uint_as_float(p & 0xFFFF0000u); }

// ---------------- ELL build (ushort ids), XCD-partitioned (round-7 win) ----------------

__global__ __launch_bounds__(256) void fill_ell_part(const int* __restrict__ src,
                                                     const int* __restrict__ dst,
                                                     int* __restrict__ cnt,
                                                     unsigned short* __restrict__ ell) {
    int chunk = blockIdx.x >> 3;
    int p     = blockIdx.x & 7;
    int e = chunk * 256 + threadIdx.x;
    if (e >= NE) return;
    int d = dst[e];
    if (d / 6250 != p) return;
    int pos = atomicAdd(&cnt[d], 1);
    if (pos < MAXDEG) ell[d * MAXDEG + pos] = (unsigned short)src[e];
}

// deg clamp + D^{-1/2} + degree histogram (LDS-aggregated) + sentinel zeroing
__global__ __launch_bounds__(256) void dinv_kernel(int* __restrict__ cnt,
                                                   float* __restrict__ dinv,
                                                   int* __restrict__ hist,
                                                   unsigned short* __restrict__ hb0,
                                                   unsigned short* __restrict__ hb1) {
    __shared__ int lh[NBINS];
    int tid = threadIdx.x;
    if (tid < NBINS) lh[tid] = 0;
    __syncthreads();
    int i = blockIdx.x * 256 + tid;
    if (i < NN) {
        int c = cnt[i];
        if (c > MAXDEG) c = MAXDEG;
        cnt[i] = c;
        dinv[i] = rsqrtf((float)(c < 1 ? 1 : c));
        atomicAdd(&lh[c], 1);
    }
    if (i < HF) {
        hb0[(size_t)NN * HF + i] = 0;
        hb1[(size_t)NN * HF + i] = 0;
    }
    __syncthreads();
    if (tid < NBINS && lh[tid] > 0) atomicAdd(&hist[tid], lh[tid]);
}

// one wave: exclusive scan of the 65-bin histogram -> bin cursors
__global__ __launch_bounds__(64) void scan_bins(const int* __restrict__ hist,
                                                int* __restrict__ cursor) {
    int t = threadIdx.x;            // 0..63
    int v = hist[t];
    int s = v;
#pragma unroll
    for (int off = 1; off < 64; off <<= 1) {
        int u = __shfl_up(s, off);
        if (t >= off) s += u;
    }
    cursor[t] = s - v;              // exclusive prefix for bins 0..63
    if (t == 63) cursor[64] = s;    // bin 64 starts after all of 0..63
}

// hierarchical scatter into degree-sorted permutation:
// LDS rank within block, <=65 global atomics per block (Guideline 12 —
// round-13's per-node atomicAdd on 65 counters cost 137us).
__global__ __launch_bounds__(256) void perm_fill(const int* __restrict__ cnt,
                                                 int* __restrict__ cursor,
                                                 int* __restrict__ perm) {
    __shared__ int lcnt[NBINS];
    __shared__ int lbase[NBINS];
    int tid = threadIdx.x;
    if (tid < NBINS) lcnt[tid] = 0;
    __syncthreads();
    int i = blockIdx.x * 256 + tid;
    int bin = 0, rank = 0;
    if (i < NN) {
        bin = cnt[i];
        rank = atomicAdd(&lcnt[bin], 1);   // LDS atomic: fast
    }
    __syncthreads();
    if (tid < NBINS && lcnt[tid] > 0)
        lbase[tid] = atomicAdd(&cursor[tid], lcnt[tid]);  // one global RMW per bin per block
    __syncthreads();
    if (i < NN) perm[lbase[bin] + rank] = i;
}

// ---------------- merged B-fragment pack + cnt/hist zero-init ----------------
// frag index: [kc][nt][lane][j], value = B[k = kc*32 + (lane>>4)*8 + j][n = nt*16 + (lane&15)]

__global__ void pack_b(const float* __restrict__ W1, const float* __restrict__ W2,
                       unsigned short* __restrict__ Bp1, unsigned short* __restrict__ Bp2,
                       int* __restrict__ cnt, int* __restrict__ hist) {
    int gid = blockIdx.x * 256 + threadIdx.x;  // 80*256 = 20480 threads
    for (int z = gid; z < NN + NBINS; z += 20480) {
        if (z < NN) cnt[z] = 0;
        else        hist[z - NN] = 0;
    }
    if (gid >= 20480) return;
    if (gid < 8192) {
        int j  = gid & 7;
        int l  = (gid >> 3) & 63;
        int nt = (gid >> 9) & 3;
        int kc = gid >> 11;
        int n = nt * 16 + (l & 15);
        int k = kc * 32 + (l >> 4) * 8 + j;
        Bp1[gid] = f2bf(W1[n * INF + k]);  // B[k][n] = W1[n][k]
    } else {
        int g = gid - 8192;
        int j  = g & 7;
        int l  = (g >> 3) & 63;
        int nt = (g >> 9) & 3;
        int kc = g >> 11;  // 0..5
        int n = nt * 16 + (l & 15);
        int k = kc * 32 + (l >> 4) * 8 + j;  // 0..191
        const float* row = W2 + (size_t)n * K2;
        float v;
        if (k < 64) {
            v = 3.0f * row[k];
        } else if (k < 128) {
            int c = k - 64;
            v = -3.0f * row[c] + 3.0f * row[64 + c];
        } else {
            int c = k - 128;
            v = 0.75f * row[c] - 1.5f * row[64 + c] + 0.75f * row[128 + c];
        }
        Bp2[g] = f2bf(v);
    }
}

// ---------------- GEMM1 (MFMA): xb = relu(F@W1^T+b1), hb0 = xb*dinv (both bf16) ----

__global__ __launch_bounds__(256) void gemm1_mfma(const float* __restrict__ F,
                                                  const unsigned short* __restrict__ Bp,
                                                  const float* __restrict__ b1,
                                                  const float* __restrict__ dinv,
                                                  unsigned short* __restrict__ xb,
                                                  unsigned short* __restrict__ hb0) {
    int tid  = threadIdx.x;
    int lane = tid & 63;
    int wv   = tid >> 6;
    int m0   = blockIdx.x * 64 + wv * 16;
    if (m0 >= NN) return;                 // NN % 16 == 0
    int mrow = lane & 15;
    int q    = lane >> 4;

    float4v acc[4];
#pragma unroll
    for (int nt = 0; nt < 4; ++nt) acc[nt] = (float4v){0.f, 0.f, 0.f, 0.f};

    const float* arow = F + (size_t)(m0 + mrow) * INF + q * 8;
#pragma unroll
    for (int kc = 0; kc < INF / 32; ++kc) {
        const float* ap = arow + kc * 32;
        float4v a0 = *reinterpret_cast<const float4v*>(ap);
        float4v a1 = *reinterpret_cast<const float4v*>(ap + 4);
        short8 af;
        af[0] = (short)f2bf(a0[0]); af[1] = (short)f2bf(a0[1]);
        af[2] = (short)f2bf(a0[2]); af[3] = (short)f2bf(a0[3]);
        af[4] = (short)f2bf(a1[0]); af[5] = (short)f2bf(a1[1]);
        af[6] = (short)f2bf(a1[2]); af[7] = (short)f2bf(a1[3]);
#pragma unroll
        for (int nt = 0; nt < 4; ++nt) {
            short8 bf = *reinterpret_cast<const short8*>(Bp + (((kc * 4 + nt) * 64 + lane) << 3));
            acc[nt] = __builtin_amdgcn_mfma_f32_16x16x32_bf16(af, bf, acc[nt], 0, 0, 0);
        }
    }

    float dn[4];
#pragma unroll
    for (int r = 0; r < 4; ++r) dn[r] = dinv[m0 + q * 4 + r];

#pragma unroll
    for (int nt = 0; nt < 4; ++nt) {
        int n = nt * 16 + mrow;
        float bv = b1[n];
#pragma unroll
        for (int r = 0; r < 4; ++r) {
            int node = m0 + q * 4 + r;
            float v = acc[nt][r] + bv;
            v = v > 0.0f ? v : 0.0f;
            xb [(size_t)node * HF + n] = f2bf(v);
            hb0[(size_t)node * HF + n] = f2bf(v * dn[r]);
        }
    }
}

// ---------------- quad gather, degree-sorted: 4 nodes/wave, 16 lanes/node ----

template <bool WRITE_H>
__global__ __launch_bounds__(256) void gather_quad(const int* __restrict__ perm,
                                                   const unsigned short* __restrict__ ell,
                                                   const int* __restrict__ cnt,
                                                   const float* __restrict__ dinv,
                                                   const unsigned short* __restrict__ fin,
                                                   const unsigned short* __restrict__ hb,
                                                   unsigned short* __restrict__ fout,
                                                   unsigned short* __restrict__ hout) {
    int lane  = threadIdx.x & 63;
    int wv    = threadIdx.x >> 6;
    int which = lane >> 4;        // 0..3: which node of the quad
    int jj    = lane & 15;        // 8B chunk index within 128B row
    int n = perm[blockIdx.x * 16 + wv * 4 + which];   // 3125*16 = 50000
    int deg = cnt[n];

    ushort4v ids = *reinterpret_cast<const ushort4v*>(ell + (size_t)n * MAXDEG + jj * 4);
    int slot = jj * 4;
    int s0 = (slot + 0 < deg) ? (int)ids[0] : NN;
    int s1 = (slot + 1 < deg) ? (int)ids[1] : NN;
    int s2 = (slot + 2 < deg) ? (int)ids[2] : NN;
    int s3 = (slot + 3 < deg) ? (int)ids[3] : NN;

    int wmax = deg;
    wmax = max(wmax, __shfl_xor(wmax, 16));
    wmax = max(wmax, __shfl_xor(wmax, 32));

    const uint2v* hbd = (const uint2v*)hb;   // row stride 16 x 8B
    int base = which * 16;

    float a0=0,a1=0,a2=0,a3=0;
    float b0=0,b1=0,b2=0,b3=0;
    float c0=0,c1=0,c2=0,c3=0;
    float d0=0,d1=0,d2=0,d3=0;

    for (int k = 0; k < wmax; k += 4) {
        int o = base + (k >> 2);
        int t0 = __shfl(s0, o), t1 = __shfl(s1, o);
        int t2 = __shfl(s2, o), t3 = __shfl(s3, o);
        uint2v p0 = hbd[(size_t)t0 * 16 + jj];
        uint2v p1 = hbd[(size_t)t1 * 16 + jj];
        uint2v p2 = hbd[(size_t)t2 * 16 + jj];
        uint2v p3 = hbd[(size_t)t3 * 16 + jj];
        a0 += bflo(p0[0]); a1 += bfhi(p0[0]); a2 += bflo(p0[1]); a3 += bfhi(p0[1]);
        b0 += bflo(p1[0]); b1 += bfhi(p1[0]); b2 += bflo(p1[1]); b3 += bfhi(p1[1]);
        c0 += bflo(p2[0]); c1 += bfhi(p2[0]); c2 += bflo(p2[1]); c3 += bfhi(p2[1]);
        d0 += bflo(p3[0]); d1 += bfhi(p3[0]); d2 += bflo(p3[1]); d3 += bfhi(p3[1]);
    }
    float e0 = (a0 + b0) + (c0 + d0);
    float e1 = (a1 + b1) + (c1 + d1);
    float e2 = (a2 + b2) + (c2 + d2);
    float e3 = (a3 + b3) + (c3 + d3);
    float dn = dinv[n];

    uint2v xv = ((const uint2v*)fin)[(size_t)n * 16 + jj];
    float f0 = bflo(xv[0]) - e0 * dn;
    float f1 = bfhi(xv[0]) - e1 * dn;
    float f2 = bflo(xv[1]) - e2 * dn;
    float f3 = bfhi(xv[1]) - e3 * dn;
    uint2v ov;
    ov[0] = (unsigned int)f2bf(f0) | ((unsigned int)f2bf(f1) << 16);
    ov[1] = (unsigned int)f2bf(f2) | ((unsigned int)f2bf(f3) << 16);
    ((uint2v*)fout)[(size_t)n * 16 + jj] = ov;
    if (WRITE_H) {
        uint2v hv;
        hv[0] = (unsigned int)f2bf(f0 * dn) | ((unsigned int)f2bf(f1 * dn) << 16);
        hv[1] = (unsigned int)f2bf(f2 * dn) | ((unsigned int)f2bf(f3 * dn) << 16);
        ((uint2v*)hout)[(size_t)n * 16 + jj] = hv;
    }
}

// ---------------- GEMM2 (MFMA): out = [xb|f1b|f2b] @ McT + b2 ----------------

__global__ __launch_bounds__(256) void gemm2_mfma(const unsigned short* __restrict__ xb,
                                                  const unsigned short* __restrict__ f1b,
                                                  const unsigned short* __restrict__ f2b,
                                                  const unsigned short* __restrict__ Bp,
                                                  const float* __restrict__ b2,
                                                  float* __restrict__ out) {
    int tid  = threadIdx.x;
    int lane = tid & 63;
    int wv   = tid >> 6;
    int m0   = blockIdx.x * 64 + wv * 16;
    if (m0 >= NN) return;
    int mrow = lane & 15;
    int q    = lane >> 4;

    float4v acc[4];
#pragma unroll
    for (int nt = 0; nt < 4; ++nt) acc[nt] = (float4v){0.f, 0.f, 0.f, 0.f};

    const unsigned short* ax = xb  + (size_t)(m0 + mrow) * HF + q * 8;
    const unsigned short* a1 = f1b + (size_t)(m0 + mrow) * HF + q * 8;
    const unsigned short* a2 = f2b + (size_t)(m0 + mrow) * HF + q * 8;

#pragma unroll
    for (int kc = 0; kc < 6; ++kc) {
        short8 af;
        if (kc < 2)      af = *reinterpret_cast<const short8*>(ax + kc * 32);
        else if (kc < 4) af = *reinterpret_cast<const short8*>(a1 + (kc - 2) * 32);
        else             af = *reinterpret_cast<const short8*>(a2 + (kc - 4) * 32);
#pragma unroll
        for (int nt = 0; nt < 4; ++nt) {
            short8 bf = *reinterpret_cast<const short8*>(Bp + (((kc * 4 + nt) * 64 + lane) << 3));
            acc[nt] = __builtin_amdgcn_mfma_f32_16x16x32_bf16(af, bf, acc[nt], 0, 0, 0);
        }
    }

#pragma unroll
    for (int nt = 0; nt < 4; ++nt) {
        int n = nt * 16 + mrow;
        float bv = b2[n];
#pragma unroll
        for (int r = 0; r < 4; ++r) {
            int node = m0 + q * 4 + r;
            out[(size_t)node * HF + n] = acc[nt][r] + bv;
        }
    }
}

// ---------------- launch ----------------

extern "C" void kernel_launch(void* const* d_in, const int* in_sizes, int n_in,
                              void* d_out, int out_size, void* d_ws, size_t ws_size,
                              hipStream_t stream) {
    const float* features = (const float*)d_in[0];
    const int*   src      = (const int*)d_in[1];
    const int*   dst      = (const int*)d_in[2];
    const float* W1       = (const float*)d_in[3];
    const float* b1       = (const float*)d_in[4];
    const float* W2       = (const float*)d_in[5];
    const float* b2       = (const float*)d_in[6];
    float* out = (float*)d_out;

    // workspace layout (bf16 64-stride feature buffers; hb0/hb1 have a zero
    // sentinel row at index NN for the quad gather)
    unsigned short* xb  = (unsigned short*)d_ws;          // NN*64      f0
    unsigned short* hb0 = xb  + (size_t)NN * HF;          // (NN+1)*64  f0*dinv
    unsigned short* f1b = hb0 + (size_t)(NN + 1) * HF;    // NN*64      f1
    unsigned short* hb1 = f1b + (size_t)NN * HF;          // (NN+1)*64  f1*dinv
    unsigned short* f2b = hb1 + (size_t)(NN + 1) * HF;    // NN*64      f2
    unsigned short* Bp1 = f2b + (size_t)NN * HF;          // 8192
    unsigned short* Bp2 = Bp1 + 8192;                     // 12288
    unsigned short* ell = Bp2 + 12288;                    // NN*64 ushort
    int*   cnt    = (int*)(ell + (size_t)NN * MAXDEG);    // NN
    float* dinv   = (float*)(cnt + NN);                   // NN
    int*   hist   = (int*)(dinv + NN);                    // NBINS
    int*   cursor = hist + NBINS;                         // NBINS
    int*   perm   = cursor + NBINS;                       // NN

    // weight pack + cnt/hist zero-init (replaces memsetAsync)
    pack_b<<<80, 256, 0, stream>>>(W1, W2, Bp1, Bp2, cnt, hist);

    // ELL build (XCD-partitioned scatter, ushort ids)
    fill_ell_part<<<((NE + 255) / 256) * 8, 256, 0, stream>>>(src, dst, cnt, ell);

    // normalization + degree histogram + sentinel zero
    dinv_kernel<<<(NN + 255) / 256, 256, 0, stream>>>(cnt, dinv, hist, hb0, hb1);

    // degree-sorted permutation (counting sort, hierarchical scatter)
    scan_bins<<<1, 64, 0, stream>>>(hist, cursor);
    perm_fill<<<(NN + 255) / 256, 256, 0, stream>>>(cnt, cursor, perm);

    // GEMM1 (MFMA) -> xb, hb0
    gemm1_mfma<<<(NN + 63) / 64, 256, 0, stream>>>(features, Bp1, b1, dinv, xb, hb0);

    // Laplacian chain: degree-sorted quad gathers
    gather_quad<true ><<<NN / 16, 256, 0, stream>>>(perm, ell, cnt, dinv, xb,  hb0, f1b, hb1);
    gather_quad<false><<<NN / 16, 256, 0, stream>>>(perm, ell, cnt, dinv, f1b, hb1, f2b, nullptr);

    // output GEMM
    gemm2_mfma<<<(NN + 63) / 64, 256, 0, stream>>>(xb, f1b, f2b, Bp2, b2, out);
}

// Round 15
// 169.437 us; speedup vs baseline: 1.8365x; 1.0403x over previous
//
#include <hip/hip_runtime.h>

#define NN 50000
#define NE 800000
#define INF 128
#define HF 64
#define K2 192
#define MAXDEG 64

typedef __attribute__((ext_vector_type(8))) short short8;
typedef __attribute__((ext_vector_type(4))) float float4v;
typedef __attribute__((ext_vector_type(4))) unsigned short ushort4v;
typedef __attribute__((ext_vector_type(2))) unsigned int uint2v;

// float -> bf16 bits, round-to-nearest-even (data has no NaN/Inf)
__device__ inline unsigned short f2bf(float x) {
    unsigned int u = __float_as_uint(x);
    u += 0x7FFFu + ((u >> 16) & 1u);
    return (unsigned short)(u >> 16);
}
__device__ inline float bflo(unsigned int p) { return __uint_as_float(p << 16); }
__device__ inline float bfhi(unsigned int p) { return __uint_as_float(p & 0xFFFF0000u); }

// ---------------- ELL build (ushort ids), XCD-partitioned (round-7 win) ----------------

__global__ __launch_bounds__(256) void fill_ell_part(const int* __restrict__ src,
                                                     const int* __restrict__ dst,
                                                     int* __restrict__ cnt,
                                                     unsigned short* __restrict__ ell) {
    int chunk = blockIdx.x >> 3;
    int p     = blockIdx.x & 7;
    int e = chunk * 256 + threadIdx.x;
    if (e >= NE) return;
    int d = dst[e];
    if (d / 6250 != p) return;
    int pos = atomicAdd(&cnt[d], 1);
    if (pos < MAXDEG) ell[d * MAXDEG + pos] = (unsigned short)src[e];
}

// deg clamp + D^{-1/2} + zero the sentinel row NN of hb0/hb1
__global__ __launch_bounds__(256) void dinv_kernel(int* __restrict__ cnt,
                                                   float* __restrict__ dinv,
                                                   unsigned short* __restrict__ hb0,
                                                   unsigned short* __restrict__ hb1) {
    int i = blockIdx.x * 256 + threadIdx.x;
    if (i < NN) {
        int c = cnt[i];
        if (c > MAXDEG) c = MAXDEG;
        cnt[i] = c;
        dinv[i] = rsqrtf((float)(c < 1 ? 1 : c));
    }
    if (i < HF) {
        hb0[(size_t)NN * HF + i] = 0;
        hb1[(size_t)NN * HF + i] = 0;
    }
}

// ---------------- merged B-fragment pack + cnt zero-init ----------------
// frag index: [kc][nt][lane][j], value = B[k = kc*32 + (lane>>4)*8 + j][n = nt*16 + (lane&15)]

__global__ void pack_b(const float* __restrict__ W1, const float* __restrict__ W2,
                       unsigned short* __restrict__ Bp1, unsigned short* __restrict__ Bp2,
                       int* __restrict__ cnt) {
    int gid = blockIdx.x * 256 + threadIdx.x;  // 80*256 = 20480 threads
    for (int z = gid; z < NN; z += 20480) cnt[z] = 0;
    if (gid >= 20480) return;
    if (gid < 8192) {
        int j  = gid & 7;
        int l  = (gid >> 3) & 63;
        int nt = (gid >> 9) & 3;
        int kc = gid >> 11;
        int n = nt * 16 + (l & 15);
        int k = kc * 32 + (l >> 4) * 8 + j;
        Bp1[gid] = f2bf(W1[n * INF + k]);  // B[k][n] = W1[n][k]
    } else {
        int g = gid - 8192;
        int j  = g & 7;
        int l  = (g >> 3) & 63;
        int nt = (g >> 9) & 3;
        int kc = g >> 11;  // 0..5
        int n = nt * 16 + (l & 15);
        int k = kc * 32 + (l >> 4) * 8 + j;  // 0..191
        const float* row = W2 + (size_t)n * K2;
        float v;
        if (k < 64) {
            v = 3.0f * row[k];
        } else if (k < 128) {
            int c = k - 64;
            v = -3.0f * row[c] + 3.0f * row[64 + c];
        } else {
            int c = k - 128;
            v = 0.75f * row[c] - 1.5f * row[64 + c] + 0.75f * row[128 + c];
        }
        Bp2[g] = f2bf(v);
    }
}

// ---------------- GEMM1 (MFMA): xb = relu(F@W1^T+b1), hb0 = xb*dinv (both bf16) ----

__global__ __launch_bounds__(256) void gemm1_mfma(const float* __restrict__ F,
                                                  const unsigned short* __restrict__ Bp,
                                                  const float* __restrict__ b1,
                                                  const float* __restrict__ dinv,
                                                  unsigned short* __restrict__ xb,
                                                  unsigned short* __restrict__ hb0) {
    int tid  = threadIdx.x;
    int lane = tid & 63;
    int wv   = tid >> 6;
    int m0   = blockIdx.x * 64 + wv * 16;
    if (m0 >= NN) return;                 // NN % 16 == 0
    int mrow = lane & 15;
    int q    = lane >> 4;

    float4v acc[4];
#pragma unroll
    for (int nt = 0; nt < 4; ++nt) acc[nt] = (float4v){0.f, 0.f, 0.f, 0.f};

    const float* arow = F + (size_t)(m0 + mrow) * INF + q * 8;
#pragma unroll
    for (int kc = 0; kc < INF / 32; ++kc) {
        const float* ap = arow + kc * 32;
        float4v a0 = *reinterpret_cast<const float4v*>(ap);
        float4v a1 = *reinterpret_cast<const float4v*>(ap + 4);
        short8 af;
        af[0] = (short)f2bf(a0[0]); af[1] = (short)f2bf(a0[1]);
        af[2] = (short)f2bf(a0[2]); af[3] = (short)f2bf(a0[3]);
        af[4] = (short)f2bf(a1[0]); af[5] = (short)f2bf(a1[1]);
        af[6] = (short)f2bf(a1[2]); af[7] = (short)f2bf(a1[3]);
#pragma unroll
        for (int nt = 0; nt < 4; ++nt) {
            short8 bf = *reinterpret_cast<const short8*>(Bp + (((kc * 4 + nt) * 64 + lane) << 3));
            acc[nt] = __builtin_amdgcn_mfma_f32_16x16x32_bf16(af, bf, acc[nt], 0, 0, 0);
        }
    }

    float dn[4];
#pragma unroll
    for (int r = 0; r < 4; ++r) dn[r] = dinv[m0 + q * 4 + r];

#pragma unroll
    for (int nt = 0; nt < 4; ++nt) {
        int n = nt * 16 + mrow;
        float bv = b1[n];
#pragma unroll
        for (int r = 0; r < 4; ++r) {
            int node = m0 + q * 4 + r;
            float v = acc[nt][r] + bv;
            v = v > 0.0f ? v : 0.0f;
            xb [(size_t)node * HF + n] = f2bf(v);
            hb0[(size_t)node * HF + n] = f2bf(v * dn[r]);
        }
    }
}

// ---------------- quad gather (unsorted — round-12 best): 4 nodes/wave ----
// fout = fin - (sum_in hb[s]) * dinv[n]; optional hout = fout*dinv[n].
// 16 lanes/node, 8B (4-feature) lanes: one VMEM instruction serves 4 rows x 128B.
// Out-of-degree ELL slots -> zero sentinel row NN (no predication in hot loop).

template <bool WRITE_H>
__global__ __launch_bounds__(256) void gather_quad(const unsigned short* __restrict__ ell,
                                                   const int* __restrict__ cnt,
                                                   const float* __restrict__ dinv,
                                                   const unsigned short* __restrict__ fin,
                                                   const unsigned short* __restrict__ hb,
                                                   unsigned short* __restrict__ fout,
                                                   unsigned short* __restrict__ hout) {
    int lane  = threadIdx.x & 63;
    int wv    = threadIdx.x >> 6;
    int which = lane >> 4;        // 0..3: which node of the quad
    int jj    = lane & 15;        // 8B chunk index within 128B row
    int n = blockIdx.x * 16 + wv * 4 + which;   // 3125*16 = 50000: always valid
    int deg = cnt[n];

    ushort4v ids = *reinterpret_cast<const ushort4v*>(ell + (size_t)n * MAXDEG + jj * 4);
    int slot = jj * 4;
    int s0 = (slot + 0 < deg) ? (int)ids[0] : NN;
    int s1 = (slot + 1 < deg) ? (int)ids[1] : NN;
    int s2 = (slot + 2 < deg) ? (int)ids[2] : NN;
    int s3 = (slot + 3 < deg) ? (int)ids[3] : NN;

    // wave-max degree across the 4 node groups
    int wmax = deg;
    wmax = max(wmax, __shfl_xor(wmax, 16));
    wmax = max(wmax, __shfl_xor(wmax, 32));

    const uint2v* hbd = (const uint2v*)hb;   // row stride 16 x 8B
    int base = which * 16;

    float a0=0,a1=0,a2=0,a3=0;
    float b0=0,b1=0,b2=0,b3=0;
    float c0=0,c1=0,c2=0,c3=0;
    float d0=0,d1=0,d2=0,d3=0;

    for (int k = 0; k < wmax; k += 4) {
        int o = base + (k >> 2);
        int t0 = __shfl(s0, o), t1 = __shfl(s1, o);
        int t2 = __shfl(s2, o), t3 = __shfl(s3, o);
        uint2v p0 = hbd[(size_t)t0 * 16 + jj];
        uint2v p1 = hbd[(size_t)t1 * 16 + jj];
        uint2v p2 = hbd[(size_t)t2 * 16 + jj];
        uint2v p3 = hbd[(size_t)t3 * 16 + jj];
        a0 += bflo(p0[0]); a1 += bfhi(p0[0]); a2 += bflo(p0[1]); a3 += bfhi(p0[1]);
        b0 += bflo(p1[0]); b1 += bfhi(p1[0]); b2 += bflo(p1[1]); b3 += bfhi(p1[1]);
        c0 += bflo(p2[0]); c1 += bfhi(p2[0]); c2 += bflo(p2[1]); c3 += bfhi(p2[1]);
        d0 += bflo(p3[0]); d1 += bfhi(p3[0]); d2 += bflo(p3[1]); d3 += bfhi(p3[1]);
    }
    float e0 = (a0 + b0) + (c0 + d0);
    float e1 = (a1 + b1) + (c1 + d1);
    float e2 = (a2 + b2) + (c2 + d2);
    float e3 = (a3 + b3) + (c3 + d3);
    float dn = dinv[n];

    uint2v xv = ((const uint2v*)fin)[(size_t)n * 16 + jj];
    float f0 = bflo(xv[0]) - e0 * dn;
    float f1 = bfhi(xv[0]) - e1 * dn;
    float f2 = bflo(xv[1]) - e2 * dn;
    float f3 = bfhi(xv[1]) - e3 * dn;
    uint2v ov;
    ov[0] = (unsigned int)f2bf(f0) | ((unsigned int)f2bf(f1) << 16);
    ov[1] = (unsigned int)f2bf(f2) | ((unsigned int)f2bf(f3) << 16);
    ((uint2v*)fout)[(size_t)n * 16 + jj] = ov;
    if (WRITE_H) {
        uint2v hv;
        hv[0] = (unsigned int)f2bf(f0 * dn) | ((unsigned int)f2bf(f1 * dn) << 16);
        hv[1] = (unsigned int)f2bf(f2 * dn) | ((unsigned int)f2bf(f3 * dn) << 16);
        ((uint2v*)hout)[(size_t)n * 16 + jj] = hv;
    }
}

// ---------------- GEMM2 (MFMA): out = [xb|f1b|f2b] @ McT + b2 ----------------

__global__ __launch_bounds__(256) void gemm2_mfma(const unsigned short* __restrict__ xb,
                                                  const unsigned short* __restrict__ f1b,
                                                  const unsigned short* __restrict__ f2b,
                                                  const unsigned short* __restrict__ Bp,
                                                  const float* __restrict__ b2,
                                                  float* __restrict__ out) {
    int tid  = threadIdx.x;
    int lane = tid & 63;
    int wv   = tid >> 6;
    int m0   = blockIdx.x * 64 + wv * 16;
    if (m0 >= NN) return;
    int mrow = lane & 15;
    int q    = lane >> 4;

    float4v acc[4];
#pragma unroll
    for (int nt = 0; nt < 4; ++nt) acc[nt] = (float4v){0.f, 0.f, 0.f, 0.f};

    const unsigned short* ax = xb  + (size_t)(m0 + mrow) * HF + q * 8;
    const unsigned short* a1 = f1b + (size_t)(m0 + mrow) * HF + q * 8;
    const unsigned short* a2 = f2b + (size_t)(m0 + mrow) * HF + q * 8;

#pragma unroll
    for (int kc = 0; kc < 6; ++kc) {
        short8 af;
        if (kc < 2)      af = *reinterpret_cast<const short8*>(ax + kc * 32);
        else if (kc < 4) af = *reinterpret_cast<const short8*>(a1 + (kc - 2) * 32);
        else             af = *reinterpret_cast<const short8*>(a2 + (kc - 4) * 32);
#pragma unroll
        for (int nt = 0; nt < 4; ++nt) {
            short8 bf = *reinterpret_cast<const short8*>(Bp + (((kc * 4 + nt) * 64 + lane) << 3));
            acc[nt] = __builtin_amdgcn_mfma_f32_16x16x32_bf16(af, bf, acc[nt], 0, 0, 0);
        }
    }

#pragma unroll
    for (int nt = 0; nt < 4; ++nt) {
        int n = nt * 16 + mrow;
        float bv = b2[n];
#pragma unroll
        for (int r = 0; r < 4; ++r) {
            int node = m0 + q * 4 + r;
            out[(size_t)node * HF + n] = acc[nt][r] + bv;
        }
    }
}

// ---------------- launch ----------------

extern "C" void kernel_launch(void* const* d_in, const int* in_sizes, int n_in,
                              void* d_out, int out_size, void* d_ws, size_t ws_size,
                              hipStream_t stream) {
    const float* features = (const float*)d_in[0];
    const int*   src      = (const int*)d_in[1];
    const int*   dst      = (const int*)d_in[2];
    const float* W1       = (const float*)d_in[3];
    const float* b1       = (const float*)d_in[4];
    const float* W2       = (const float*)d_in[5];
    const float* b2       = (const float*)d_in[6];
    float* out = (float*)d_out;

    // workspace layout (bf16 64-stride feature buffers; hb0/hb1 have a zero
    // sentinel row at index NN for the quad gather)
    unsigned short* xb  = (unsigned short*)d_ws;          // NN*64      f0
    unsigned short* hb0 = xb  + (size_t)NN * HF;          // (NN+1)*64  f0*dinv
    unsigned short* f1b = hb0 + (size_t)(NN + 1) * HF;    // NN*64      f1
    unsigned short* hb1 = f1b + (size_t)NN * HF;          // (NN+1)*64  f1*dinv
    unsigned short* f2b = hb1 + (size_t)(NN + 1) * HF;    // NN*64      f2
    unsigned short* Bp1 = f2b + (size_t)NN * HF;          // 8192
    unsigned short* Bp2 = Bp1 + 8192;                     // 12288
    unsigned short* ell = Bp2 + 12288;                    // NN*64 ushort
    int*   cnt  = (int*)(ell + (size_t)NN * MAXDEG);      // NN
    float* dinv = (float*)(cnt + NN);                     // NN

    // weight pack + cnt zero-init (no separate memset dispatch)
    pack_b<<<80, 256, 0, stream>>>(W1, W2, Bp1, Bp2, cnt);

    // ELL build (XCD-partitioned scatter, ushort ids)
    fill_ell_part<<<((NE + 255) / 256) * 8, 256, 0, stream>>>(src, dst, cnt, ell);

    // normalization + sentinel zero
    dinv_kernel<<<(NN + 255) / 256, 256, 0, stream>>>(cnt, dinv, hb0, hb1);

    // GEMM1 (MFMA) -> xb, hb0
    gemm1_mfma<<<(NN + 63) / 64, 256, 0, stream>>>(features, Bp1, b1, dinv, xb, hb0);

    // Laplacian chain: quad gathers (4 nodes/wave, 8B lanes, natural node order)
    gather_quad<true ><<<NN / 16, 256, 0, stream>>>(ell, cnt, dinv, xb,  hb0, f1b, hb1);
    gather_quad<false><<<NN / 16, 256, 0, stream>>>(ell, cnt, dinv, f1b, hb1, f2b, nullptr);

    // output GEMM
    gemm2_mfma<<<(NN + 63) / 64, 256, 0, stream>>>(xb, f1b, f2b, Bp2, b2, out);
}